// Round 2
// baseline (201.452 us; speedup 1.0000x reference)
//
#include <hip/hip_runtime.h>

// ToBEVReduction: sorted-unique over 27-bit packed coords + segment mean.
// Pipeline: bitmap -> hierarchical popcount scan (fused with sorted-unique
// enumeration) -> per-element rank -> gather (sequential writes, random reads).
// count==1 segments (~99.85%) are plain copies; rare count>1 rows are zeroed
// in the gather then atomically accumulated with the 1/cnt fold.

#define NWORDS      (1u << 22)              // 2^27 bits / 32
#define SCAN_BLOCKS 1024
#define WPB         (NWORDS / SCAN_BLOCKS)  // 4096 words per block
#define WPT         (WPB / 256)             // 16 words per thread

__device__ __forceinline__ unsigned key_of(const int* __restrict__ coords, int i) {
    // non-Z dims are columns 0, 2, 3 (Z_DIM = 1); each in [0, 512)
    int c0 = coords[(size_t)i * 4 + 0];
    int c1 = coords[(size_t)i * 4 + 2];
    int c2 = coords[(size_t)i * 4 + 3];
    return ((unsigned)c0 << 18) | ((unsigned)c1 << 9) | (unsigned)c2;
}

__global__ void k_build(const int* __restrict__ coords, unsigned* __restrict__ bitmap,
                        unsigned* __restrict__ keys, int N) {
    int i = blockIdx.x * blockDim.x + threadIdx.x;
    if (i >= N) return;
    unsigned key = key_of(coords, i);
    keys[i] = key;
    atomicOr(&bitmap[key >> 5], 1u << (key & 31u));
}

__global__ void k_scan1(const unsigned* __restrict__ bitmap, unsigned* __restrict__ blockSums) {
    __shared__ unsigned sd[256];
    const uint4* bm = (const uint4*)(bitmap + (size_t)blockIdx.x * WPB + (size_t)threadIdx.x * WPT);
    unsigned s = 0;
#pragma unroll
    for (int k = 0; k < WPT / 4; ++k) {
        uint4 v = bm[k];
        s += __popc(v.x) + __popc(v.y) + __popc(v.z) + __popc(v.w);
    }
    sd[threadIdx.x] = s;
    __syncthreads();
    for (int off = 128; off > 0; off >>= 1) {
        if ((int)threadIdx.x < off) sd[threadIdx.x] += sd[threadIdx.x + off];
        __syncthreads();
    }
    if (threadIdx.x == 0) blockSums[blockIdx.x] = sd[0];
}

__global__ void k_scan2(const unsigned* __restrict__ blockSums,
                        unsigned* __restrict__ blockOffsets,
                        unsigned* __restrict__ totalM) {
    __shared__ unsigned sd[SCAN_BLOCKS];
    int t = threadIdx.x;
    unsigned v = blockSums[t];
    sd[t] = v;
    __syncthreads();
    for (int off = 1; off < SCAN_BLOCKS; off <<= 1) {
        unsigned add = (t >= off) ? sd[t - off] : 0u;
        __syncthreads();
        sd[t] += add;
        __syncthreads();
    }
    blockOffsets[t] = sd[t] - v;  // exclusive
    if (t == SCAN_BLOCKS - 1) totalM[0] = sd[t];  // number of unique keys
}

// scan3 fused with sorted-unique enumeration: writes per-word rank offsets AND
// the output coords for every set bit (rows are monotone -> near-sequential).
__global__ void k_scan3enum(const unsigned* __restrict__ bitmap,
                            const unsigned* __restrict__ blockOffsets,
                            unsigned* __restrict__ offsets,
                            float4* __restrict__ outc) {
    __shared__ unsigned sd[256];
    size_t base = (size_t)blockIdx.x * WPB + (size_t)threadIdx.x * WPT;
    const uint4* bm = (const uint4*)(bitmap + base);
    unsigned w[WPT];
    unsigned s = 0;
#pragma unroll
    for (int k = 0; k < WPT / 4; ++k) {
        uint4 v = bm[k];
        w[k * 4 + 0] = v.x; w[k * 4 + 1] = v.y; w[k * 4 + 2] = v.z; w[k * 4 + 3] = v.w;
        s += __popc(v.x) + __popc(v.y) + __popc(v.z) + __popc(v.w);
    }
    int t = threadIdx.x;
    sd[t] = s;
    __syncthreads();
    for (int off = 1; off < 256; off <<= 1) {
        unsigned add = (t >= off) ? sd[t - off] : 0u;
        __syncthreads();
        sd[t] += add;
        __syncthreads();
    }
    unsigned run = blockOffsets[blockIdx.x] + sd[t] - s;  // exclusive prefix
#pragma unroll
    for (int k = 0; k < WPT; ++k) {
        offsets[base + k] = run;
        unsigned bits = w[k];
        while (bits) {
            int b = __ffs(bits) - 1;
            unsigned key = ((unsigned)(base + k) << 5) | (unsigned)b;
            outc[run] = make_float4((float)(key >> 18), 0.f,
                                    (float)((key >> 9) & 511u), (float)(key & 511u));
            ++run;
            bits &= bits - 1u;
        }
    }
}

__global__ void k_seg(const unsigned* __restrict__ keys,
                      const unsigned* __restrict__ bitmap,
                      const unsigned* __restrict__ offsets,
                      unsigned* __restrict__ seg,
                      unsigned* __restrict__ srcElem,
                      float* __restrict__ cnt, int N) {
    int i = blockIdx.x * blockDim.x + threadIdx.x;
    if (i >= N) return;
    unsigned key = keys[i];
    unsigned w = key >> 5, b = key & 31u;
    unsigned s = offsets[w] + __popc(bitmap[w] & ((1u << b) - 1u));
    seg[i] = s;
    srcElem[s] = i;               // single writer for count==1 rows; dup rows unused
    atomicAdd(&cnt[s], 1.0f);
}

// Sequential-write gather: out row r <- in row srcElem[r] for count==1 rows,
// zeros for pad rows (r >= M) and dup rows (pre-zero for atomic accumulation).
// Also writes the pad coords pattern for rows >= M.
__global__ void k_gather(const float4* __restrict__ fin,
                         const unsigned* __restrict__ srcElem,
                         const float* __restrict__ cnt,
                         const unsigned* __restrict__ totalM,
                         float4* __restrict__ fout,
                         float4* __restrict__ outc, int N) {
    int gid = blockIdx.x * blockDim.x + threadIdx.x;
    int r = gid >> 5;  // 32 threads (float4 each) per 128-float row
    if (r >= N) return;
    int c4 = gid & 31;
    float cv = cnt[r];
    float4 v = make_float4(0.f, 0.f, 0.f, 0.f);
    if (cv == 1.0f) {
        unsigned e = srcElem[r];
        v = fin[(size_t)e * 32 + c4];
    }
    fout[(size_t)r * 32 + c4] = v;
    if (c4 == 0 && (unsigned)r >= totalM[0]) {
        outc[r] = make_float4(-1.f, 0.f, 511.f, 511.f);  // pad row coords
    }
}

__global__ void k_dup(const float4* __restrict__ fin,
                      const unsigned* __restrict__ seg,
                      const float* __restrict__ cnt,
                      float4* __restrict__ fout, int N) {
    int i = blockIdx.x * blockDim.x + threadIdx.x;
    if (i >= N) return;
    unsigned s = seg[i];
    float cv = cnt[s];
    if (cv == 1.0f) return;  // ~99.85% exit here
    float inv = 1.0f / cv;
    float* dst = (float*)(fout + (size_t)s * 32);
#pragma unroll 4
    for (int c4 = 0; c4 < 32; ++c4) {
        float4 v = fin[(size_t)i * 32 + c4];
        atomicAdd(dst + c4 * 4 + 0, v.x * inv);
        atomicAdd(dst + c4 * 4 + 1, v.y * inv);
        atomicAdd(dst + c4 * 4 + 2, v.z * inv);
        atomicAdd(dst + c4 * 4 + 3, v.w * inv);
    }
}

extern "C" void kernel_launch(void* const* d_in, const int* in_sizes, int n_in,
                              void* d_out, int out_size, void* d_ws, size_t ws_size,
                              hipStream_t stream) {
    const float4* feat_in = (const float4*)d_in[0];
    const int* coords = (const int*)d_in[1];
    int N = in_sizes[1] / 4;  // 400000

    float* out = (float*)d_out;
    float* out_feat = out;                                    // N*128 floats
    float4* out_coords = (float4*)(out + (size_t)N * 128);    // N*4 floats
    float* out_cnt = out + (size_t)N * 132;                   // N floats

    // Scratch in d_ws (~37.5 MB; ws poison fill shows ws_size >> this)
    unsigned* bitmap = (unsigned*)d_ws;                 // 16 MB
    unsigned* offsets = bitmap + NWORDS;                // 16 MB
    unsigned* keys = offsets + NWORDS;                  // 1.6 MB
    unsigned* seg = keys + N;                           // 1.6 MB
    unsigned* srcElem = seg + N;                        // 1.6 MB
    unsigned* blockSums = srcElem + N;                  // 4 KB
    unsigned* blockOffsets = blockSums + SCAN_BLOCKS;   // 4 KB
    unsigned* totalM = blockOffsets + SCAN_BLOCKS;      // 4 B

    int nb = (N + 255) / 256;

    hipMemsetAsync(bitmap, 0, (size_t)NWORDS * 4, stream);
    hipMemsetAsync(out_cnt, 0, (size_t)N * 4, stream);

    k_build<<<nb, 256, 0, stream>>>(coords, bitmap, keys, N);
    k_scan1<<<SCAN_BLOCKS, 256, 0, stream>>>(bitmap, blockSums);
    k_scan2<<<1, SCAN_BLOCKS, 0, stream>>>(blockSums, blockOffsets, totalM);
    k_scan3enum<<<SCAN_BLOCKS, 256, 0, stream>>>(bitmap, blockOffsets, offsets, out_coords);
    k_seg<<<nb, 256, 0, stream>>>(keys, bitmap, offsets, seg, srcElem, out_cnt, N);
    k_gather<<<(int)(((size_t)N * 32 + 255) / 256), 256, 0, stream>>>(
        feat_in, srcElem, out_cnt, totalM, (float4*)out_feat, out_coords, N);
    k_dup<<<nb, 256, 0, stream>>>(feat_in, seg, out_cnt, (float4*)out_feat, N);
}

// Round 3
// 169.894 us; speedup vs baseline: 1.1857x; 1.1857x over previous
//
#include <hip/hip_runtime.h>

// ToBEVReduction: sorted-unique over 27-bit packed coords + segment mean.
// bitmap -> hierarchical popcount scan (fused with sorted enumeration of
// unique coords) -> scatter with rank computed in-kernel (sequential reads,
// random full-line writes). Duplicate segments (~0.15%) are detected via the
// count atomicAdd return value and fixed up by two tiny kernels.

#define NWORDS      (1u << 22)              // 2^27 bits / 32
#define SCAN_BLOCKS 1024
#define WPB         (NWORDS / SCAN_BLOCKS)  // 4096 words per block
#define WPT         (WPB / 256)             // 16 words per thread

typedef float f32x4 __attribute__((ext_vector_type(4)));
typedef unsigned u32;

__global__ void k_build(const int4* __restrict__ coords, u32* __restrict__ bitmap,
                        u32* __restrict__ keys, float* __restrict__ cnt,
                        u32* __restrict__ ctrs, int N) {
    int i = blockIdx.x * blockDim.x + threadIdx.x;
    if (i == 0) { ctrs[0] = 0u; ctrs[1] = 0u; }
    if (i >= N) return;
    int4 c = coords[i];  // non-Z dims are cols 0,2,3 (Z_DIM=1)
    u32 key = ((u32)c.x << 18) | ((u32)c.z << 9) | (u32)c.w;
    keys[i] = key;
    cnt[i] = 0.0f;
    atomicOr(&bitmap[key >> 5], 1u << (key & 31u));
}

__global__ void k_scan1(const u32* __restrict__ bitmap, u32* __restrict__ blockSums) {
    __shared__ u32 sd[256];
    const uint4* bm = (const uint4*)(bitmap + (size_t)blockIdx.x * WPB + (size_t)threadIdx.x * WPT);
    u32 s = 0;
#pragma unroll
    for (int k = 0; k < WPT / 4; ++k) {
        uint4 v = bm[k];
        s += __popc(v.x) + __popc(v.y) + __popc(v.z) + __popc(v.w);
    }
    sd[threadIdx.x] = s;
    __syncthreads();
    for (int off = 128; off > 0; off >>= 1) {
        if ((int)threadIdx.x < off) sd[threadIdx.x] += sd[threadIdx.x + off];
        __syncthreads();
    }
    if (threadIdx.x == 0) blockSums[blockIdx.x] = sd[0];
}

__global__ void k_scan2(const u32* __restrict__ blockSums,
                        u32* __restrict__ blockOffsets,
                        u32* __restrict__ totalM) {
    __shared__ u32 sd[SCAN_BLOCKS];
    int t = threadIdx.x;
    u32 v = blockSums[t];
    sd[t] = v;
    __syncthreads();
    for (int off = 1; off < SCAN_BLOCKS; off <<= 1) {
        u32 add = (t >= off) ? sd[t - off] : 0u;
        __syncthreads();
        sd[t] += add;
        __syncthreads();
    }
    blockOffsets[t] = sd[t] - v;  // exclusive
    if (t == SCAN_BLOCKS - 1) totalM[0] = sd[t];  // unique count M
}

// Fused: per-word {rank offset, bits} pairs AND sorted-unique coords output.
__global__ void k_scan3enum(const u32* __restrict__ bitmap,
                            const u32* __restrict__ blockOffsets,
                            uint2* __restrict__ pairs,
                            float4* __restrict__ outc) {
    __shared__ u32 sd[256];
    size_t base = (size_t)blockIdx.x * WPB + (size_t)threadIdx.x * WPT;
    const uint4* bm = (const uint4*)(bitmap + base);
    u32 w[WPT];
    u32 s = 0;
#pragma unroll
    for (int k = 0; k < WPT / 4; ++k) {
        uint4 v = bm[k];
        w[k * 4 + 0] = v.x; w[k * 4 + 1] = v.y; w[k * 4 + 2] = v.z; w[k * 4 + 3] = v.w;
        s += __popc(v.x) + __popc(v.y) + __popc(v.z) + __popc(v.w);
    }
    int t = threadIdx.x;
    sd[t] = s;
    __syncthreads();
    for (int off = 1; off < 256; off <<= 1) {
        u32 add = (t >= off) ? sd[t - off] : 0u;
        __syncthreads();
        sd[t] += add;
        __syncthreads();
    }
    u32 run = blockOffsets[blockIdx.x] + sd[t] - s;  // exclusive prefix
#pragma unroll
    for (int k = 0; k < WPT; ++k) {
        u32 bits = w[k];
        pairs[base + k] = make_uint2(run, bits);
        while (bits) {
            int b = __ffs(bits) - 1;
            u32 key = ((u32)(base + k) << 5) | (u32)b;
            outc[run] = make_float4((float)(key >> 18), 0.f,
                                    (float)((key >> 9) & 511u), (float)(key & 511u));
            ++run;
            bits &= bits - 1u;
        }
    }
}

// Heavy pass: rank lookup + duplicate bookkeeping on lane leaders, then
// streaming-read / random-full-line-write copy of the 512B feature row.
__global__ void __launch_bounds__(256) k_scatter(
        const f32x4* __restrict__ fin, const u32* __restrict__ keys,
        const uint2* __restrict__ pairs, float* __restrict__ cnt,
        u32* __restrict__ srcElem, uint2* __restrict__ dupElem,
        u32* __restrict__ dupSeg, u32* __restrict__ ctrs,
        f32x4* __restrict__ fout, int N) {
    int gid = blockIdx.x * blockDim.x + threadIdx.x;
    int elem = gid >> 5;  // 32 threads (16B each) per 128-float row
    if (elem >= N) return;
    int c4 = gid & 31;
    u32 s = 0;
    if ((threadIdx.x & 31) == 0) {
        u32 key = keys[elem];
        uint2 p = pairs[key >> 5];
        s = p.x + __popc(p.y & ((1u << (key & 31u)) - 1u));
        float old = atomicAdd(&cnt[s], 1.0f);
        if (old == 0.0f) {
            srcElem[s] = (u32)elem;  // sole element for count==1 segments
        } else {
            u32 di = atomicAdd(&ctrs[0], 1u);
            dupElem[di] = make_uint2((u32)elem, s);
            if (old == 1.0f) {  // exactly-second arrival: register segment once
                u32 ds = atomicAdd(&ctrs[1], 1u);
                dupSeg[ds] = s;
            }
        }
    }
    s = (u32)__shfl((int)s, threadIdx.x & 32);  // broadcast within each 32-lane half
    f32x4 v = __builtin_nontemporal_load(&fin[(size_t)elem * 32 + c4]);
    __builtin_nontemporal_store(v, &fout[(size_t)s * 32 + c4]);
}

// Zero the ~600 dup rows (garbage race winners) and write pad rows/coords.
__global__ void k_fix1(const u32* __restrict__ dupSeg, const u32* __restrict__ ctrs,
                       const u32* __restrict__ totalM,
                       f32x4* __restrict__ fout, float4* __restrict__ outc, int N) {
    u32 nds = ctrs[1];
    u32 M = totalM[0];
    u32 npad = (u32)N - M;
    u32 total = nds + npad;
    int gid = blockIdx.x * blockDim.x + threadIdx.x;
    int c4 = gid & 31;
    u32 stride = (gridDim.x * blockDim.x) >> 5;
    f32x4 z = {0.f, 0.f, 0.f, 0.f};
    for (u32 r = (u32)(gid >> 5); r < total; r += stride) {
        u32 row;
        bool pad = (r >= nds);
        row = pad ? (M + r - nds) : dupSeg[r];
        fout[(size_t)row * 32 + c4] = z;
        if (pad && c4 == 0) outc[row] = make_float4(-1.f, 0.f, 511.f, 511.f);
    }
}

// Accumulate mean contributions for dup segments: all displaced elements via
// dupElem, plus each segment's first-arrival element via srcElem.
__global__ void k_fix2(const f32x4* __restrict__ fin, const uint2* __restrict__ dupElem,
                       const u32* __restrict__ dupSeg, const u32* __restrict__ srcElem,
                       const float* __restrict__ cnt, const u32* __restrict__ ctrs,
                       f32x4* __restrict__ fout) {
    u32 nde = ctrs[0], nds = ctrs[1];
    u32 total = nde + nds;
    int gid = blockIdx.x * blockDim.x + threadIdx.x;
    int c4 = gid & 31;
    u32 stride = (gridDim.x * blockDim.x) >> 5;
    for (u32 t = (u32)(gid >> 5); t < total; t += stride) {
        u32 e, s;
        if (t < nde) { uint2 d = dupElem[t]; e = d.x; s = d.y; }
        else         { s = dupSeg[t - nde]; e = srcElem[s]; }
        float inv = 1.0f / cnt[s];
        f32x4 v = fin[(size_t)e * 32 + c4];
        float* dst = (float*)&fout[(size_t)s * 32 + c4];
        atomicAdd(dst + 0, v.x * inv);
        atomicAdd(dst + 1, v.y * inv);
        atomicAdd(dst + 2, v.z * inv);
        atomicAdd(dst + 3, v.w * inv);
    }
}

extern "C" void kernel_launch(void* const* d_in, const int* in_sizes, int n_in,
                              void* d_out, int out_size, void* d_ws, size_t ws_size,
                              hipStream_t stream) {
    const f32x4* feat_in = (const f32x4*)d_in[0];
    const int4* coords = (const int4*)d_in[1];
    int N = in_sizes[1] / 4;  // 400000

    float* out = (float*)d_out;
    f32x4* out_feat = (f32x4*)out;                            // N*128 floats
    float4* out_coords = (float4*)(out + (size_t)N * 128);    // N*4 floats
    float* out_cnt = out + (size_t)N * 132;                   // N floats

    // All scratch in d_ws (~52 MB; ws poison fill shows ws_size ~850 MB)
    u32* keys = (u32*)d_ws;                           // N
    u32* srcElem = keys + N;                          // N
    u32* blockSums = srcElem + N;                     // SCAN_BLOCKS
    u32* blockOffsets = blockSums + SCAN_BLOCKS;      // SCAN_BLOCKS
    u32* totalM = blockOffsets + SCAN_BLOCKS;         // 1
    u32* ctrs = totalM + 1;                           // 2 (pad to 8 for alignment)
    u32* dupSeg = ctrs + 8;                           // 65536
    uint2* dupElem = (uint2*)(dupSeg + 65536);        // 65536 uint2
    u32* bitmap = (u32*)(dupElem + 65536);            // NWORDS (16 MB)
    uint2* pairs = (uint2*)(bitmap + NWORDS);         // NWORDS uint2 (32 MB)

    int nb = (N + 255) / 256;

    hipMemsetAsync(bitmap, 0, (size_t)NWORDS * 4, stream);

    k_build<<<nb, 256, 0, stream>>>(coords, bitmap, keys, out_cnt, ctrs, N);
    k_scan1<<<SCAN_BLOCKS, 256, 0, stream>>>(bitmap, blockSums);
    k_scan2<<<1, SCAN_BLOCKS, 0, stream>>>(blockSums, blockOffsets, totalM);
    k_scan3enum<<<SCAN_BLOCKS, 256, 0, stream>>>(bitmap, blockOffsets, pairs, out_coords);
    k_scatter<<<(int)(((size_t)N * 32 + 255) / 256), 256, 0, stream>>>(
        feat_in, keys, pairs, out_cnt, srcElem, dupElem, dupSeg, ctrs, out_feat, N);
    k_fix1<<<256, 256, 0, stream>>>(dupSeg, ctrs, totalM, out_feat, out_coords, N);
    k_fix2<<<256, 256, 0, stream>>>(feat_in, dupElem, dupSeg, srcElem, out_cnt, ctrs, out_feat);
}